// Round 4
// baseline (663.703 us; speedup 1.0000x reference)
//
#include <hip/hip_runtime.h>
#include <cstdint>
#include <cstddef>

typedef short short8 __attribute__((ext_vector_type(8)));
typedef float f32x4 __attribute__((ext_vector_type(4)));

static __device__ __forceinline__ ushort f2bf(float f) {
  union { float f; uint32_t u; } v; v.f = f;
  uint32_t u = v.u + 0x7fffu + ((v.u >> 16) & 1u);  // RNE
  return (ushort)(u >> 16);
}

// Direct global->LDS copy: lane i's 16B lands at lds + i*16 (wave-uniform base).
static __device__ __forceinline__ void g2lds16(const ushort* g, ushort* lds) {
  __builtin_amdgcn_global_load_lds(
      (const __attribute__((address_space(1))) void*)(uintptr_t)g,
      (__attribute__((address_space(3))) void*)(uintptr_t)lds,
      16, 0, 0);
}

#define VMW(n) asm volatile("s_waitcnt vmcnt(" #n ")" ::: "memory")
#define BAR()  asm volatile("s_barrier" ::: "memory")

// ---------------------------------------------------------------------------
// f32 -> bf16 convert for Q and K in one dispatch (8 elem/thread).
// ---------------------------------------------------------------------------
__global__ __launch_bounds__(256) void convert_qk_bf16(
    const float* __restrict__ Q, const float* __restrict__ K,
    ushort* __restrict__ Qb, ushort* __restrict__ Kb) {
  const bool second = blockIdx.x >= 8192;
  const float* src = second ? K : Q;
  ushort* dst = second ? Kb : Qb;
  const size_t i = ((size_t)(blockIdx.x & 8191) * 256 + threadIdx.x) * 8;
  const float4 a = *(const float4*)(src + i);
  const float4 b = *(const float4*)(src + i + 4);
  ushort4 o0, o1;
  o0.x = f2bf(a.x); o0.y = f2bf(a.y); o0.z = f2bf(a.z); o0.w = f2bf(a.w);
  o1.x = f2bf(b.x); o1.y = f2bf(b.y); o1.z = f2bf(b.z); o1.w = f2bf(b.w);
  *(ushort4*)(dst + i) = o0;
  *(ushort4*)(dst + i + 4) = o1;
}

// W [1024][1024] f32 -> bf16 (for the fc_out GEMM)
__global__ __launch_bounds__(256) void convert_w_bf16(
    const float* __restrict__ W, ushort* __restrict__ Wb) {
  const size_t i = ((size_t)blockIdx.x * 256 + threadIdx.x) * 8;
  const float4 a = *(const float4*)(W + i);
  const float4 b = *(const float4*)(W + i + 4);
  ushort4 o0, o1;
  o0.x = f2bf(a.x); o0.y = f2bf(a.y); o0.z = f2bf(a.z); o0.w = f2bf(a.w);
  o1.x = f2bf(b.x); o1.y = f2bf(b.y); o1.z = f2bf(b.z); o1.w = f2bf(b.w);
  *(ushort4*)(Wb + i) = o0;
  *(ushort4*)(Wb + i + 4) = o1;
}

// ---------------------------------------------------------------------------
// V [8][2048][1024] f32 -> Vt [8][1024][2048] bf16.  64x64 tiles so every
// Vt store is a full 128B line.
// ---------------------------------------------------------------------------
__global__ __launch_bounds__(256) void transpose_convert_v(
    const float* __restrict__ V, ushort* __restrict__ Vt) {
  __shared__ float t[64][65];
  const int b = blockIdx.z;
  const int d0 = blockIdx.x * 64;   // gridDim.x = 16
  const int k0 = blockIdx.y * 64;   // gridDim.y = 32
  const float* Vb = V + (size_t)b * 2048 * 1024;
  ushort* Vtb = Vt + (size_t)b * 1024 * 2048;
  const int tx = threadIdx.x & 63, ty = threadIdx.x >> 6;   // 64 x 4
#pragma unroll
  for (int j = 0; j < 64; j += 4)
    t[ty + j][tx] = Vb[(size_t)(k0 + ty + j) * 1024 + d0 + tx];
  __syncthreads();
  const int lk = (threadIdx.x & 31) * 2;   // k-pair within tile
  const int ld = threadIdx.x >> 5;         // 0..7
#pragma unroll
  for (int p = 0; p < 8; ++p) {
    const int d = ld + p * 8;
    const uint32_t val =
        (uint32_t)f2bf(t[lk][d]) | ((uint32_t)f2bf(t[lk + 1][d]) << 16);
    *(uint32_t*)&Vtb[(size_t)(d0 + d) * 2048 + k0 + lk] = val;  // 128B/row
  }
}

// ---------------------------------------------------------------------------
// 256x256-tile "BT" GEMM: C[m][n] = f( sum_k A[m][k]*B[n][k] )
// bf16 A and B. 512 threads = 8 waves (2M x 4N), wave owns 128x64 of C
// (8x4 frags of mfma_f32_16x16x32_bf16; C/D: col=lane&15, row=quad*4+reg).
//
// Main loop (verified rounds 1-3, unchanged): ring-4 of BK=32 K-tiles
// (128 KiB LDS), counted vmcnt, 2-phase interleave per tile, raw barriers,
// setprio around MFMA clusters, XOR-granule LDS swizzle (0 bank conflicts),
// bijective XCD block swizzle.
//
// NEW (round 4): LDS-bounce epilogue. After the K-loop As/Bs are dead; stage
// raw f32 acc into S[128][256] (one half of the 256-row tile at a time,
// granule-XOR swizzled so writes are 2-way/free and reads conflict-free),
// then the 4 owning waves read back row-major: lane holds cols [4*lane,
// 4*lane+4) of one row -> ALL global IO is vectorized (float4 mask loads,
// ushort4/float4 stores, 1 atomicAdd per row per block).
//   EPI 0: C f32 = acc*scale + bias[n]                        (fc_out)
//   EPI 1: e=exp(acc*scale); C bf16 = e*mask; rowsum[m] += e  (QK^T fused
//          softmax numerator + dropout; max-subtraction skipped: scores
//          ~N(0,1), exp safe in f32)
//   EPI 2: C bf16 = acc / rowsum[m]                           (PV, denom)
// ---------------------------------------------------------------------------
template <int EPI>
__global__ __launch_bounds__(512, 2) void gemm256(
    const ushort* __restrict__ Ap, const ushort* __restrict__ Bp,
    void* __restrict__ Cp, int M, int N, int K,
    size_t sA, size_t sB, size_t sC, float scale,
    const float* __restrict__ bias, const float* __restrict__ mask,
    float* __restrict__ rowsum) {
  constexpr int BK = 32;
  // [0][*] = A ring, [1][*] = B ring; whole 128 KiB reused by the epilogue.
  __shared__ __align__(16) ushort smem[2][4][256 * BK];
  const int tid = threadIdx.x;

  // ---- T1: XCD-aware block swizzle (nwg divisible by 8 at all call sites) --
  const int gx = gridDim.x, gy = gridDim.y;
  const int nwg = gx * gy * gridDim.z;
  int li = blockIdx.x + gx * (blockIdx.y + gy * blockIdx.z);
  li = (li & 7) * (nwg >> 3) + (li >> 3);
  const int bn = li % gx;
  const int rst = li / gx;
  const int bm = rst % gy;
  const int z = rst / gy;

  const int lane = tid & 63, w = tid >> 6;   // 8 waves
  const int quad = lane >> 4, l16 = lane & 15;
  const int wm = w >> 2, wn = w & 3;         // wave tile: rows wm*128, cols wn*64
  const int NT = K >> 5;                     // K-tiles of 32

  f32x4 acc[8][4];
#pragma unroll
  for (int i = 0; i < 8; ++i)
#pragma unroll
    for (int j = 0; j < 4; ++j) acc[i][j] = (f32x4){0.f, 0.f, 0.f, 0.f};

  // ---- staging addressing (pre-swizzled global source, linear LDS dest) ----
  const int srow = w * 16 + (lane >> 2);                 // row 0..127 (round 0)
  const int sgran = (lane & 3) ^ ((lane >> 3) & 3);      // source granule
  const ushort* Abase = Ap + sA * z + (size_t)bm * 256 * K;
  const ushort* Bbase = Bp + sB * z + (size_t)bn * 256 * K;
  const ushort* Ag0 = Abase + (size_t)srow * K + sgran * 8;
  const ushort* Ag1 = Ag0 + (size_t)128 * K;
  const ushort* Bg0 = Bbase + (size_t)srow * K + sgran * 8;
  const ushort* Bg1 = Bg0 + (size_t)128 * K;
  const int ldsw0 = (w * 16) * BK;         // wave-uniform LDS row block, round 0
  const int ldsw1 = (128 + w * 16) * BK;   // round 1

  auto STAGE_A = [&](int t) {
    ushort* a = &smem[0][t & 3][0];
    const size_t ko = (size_t)t * BK;
    g2lds16(Ag0 + ko, a + ldsw0);
    g2lds16(Ag1 + ko, a + ldsw1);
  };
  auto STAGE_B = [&](int t) {
    ushort* b = &smem[1][t & 3][0];
    const size_t ko = (size_t)t * BK;
    g2lds16(Bg0 + ko, b + ldsw0);
    g2lds16(Bg1 + ko, b + ldsw1);
  };

  // ---- fragment read offsets (swizzled) ----
  const int pg = quad ^ ((l16 >> 1) & 3);                // physical granule
  const int aoff = (wm * 128 + l16) * BK + pg * 8;
  const int boff = (wn * 64 + l16) * BK + pg * 8;

  // One K-tile: 2 phases x 16 MFMA, staging of tile t+3 interleaved.
  auto TILE = [&](int t, bool stage_ok) {
    const ushort* a = &smem[0][t & 3][0];
    const ushort* b = &smem[1][t & 3][0];
    short8 bfv[4], af[4];
#pragma unroll
    for (int tn = 0; tn < 4; ++tn)
      bfv[tn] = *(const short8*)&b[boff + tn * 16 * BK];
#pragma unroll
    for (int tm = 0; tm < 4; ++tm)
      af[tm] = *(const short8*)&a[aoff + tm * 16 * BK];
    if (stage_ok) STAGE_A(t + 3);
    BAR();
    __builtin_amdgcn_s_setprio(1);
#pragma unroll
    for (int tm = 0; tm < 4; ++tm)
#pragma unroll
      for (int tn = 0; tn < 4; ++tn)
        acc[tm][tn] = __builtin_amdgcn_mfma_f32_16x16x32_bf16(
            af[tm], bfv[tn], acc[tm][tn], 0, 0, 0);
    __builtin_amdgcn_s_setprio(0);
    BAR();
    short8 af2[4];
#pragma unroll
    for (int tm = 0; tm < 4; ++tm)
      af2[tm] = *(const short8*)&a[aoff + (4 + tm) * 16 * BK];
    if (stage_ok) STAGE_B(t + 3);
    BAR();
    __builtin_amdgcn_s_setprio(1);
#pragma unroll
    for (int tm = 0; tm < 4; ++tm)
#pragma unroll
      for (int tn = 0; tn < 4; ++tn)
        acc[4 + tm][tn] = __builtin_amdgcn_mfma_f32_16x16x32_bf16(
            af2[tm], bfv[tn], acc[4 + tm][tn], 0, 0, 0);
    __builtin_amdgcn_s_setprio(0);
  };

  // ---- prologue: 3 tiles in flight ----
  STAGE_A(0); STAGE_B(0);
  STAGE_A(1); STAGE_B(1);
  STAGE_A(2); STAGE_B(2);
  // ---- main loop: counted vmcnt, collective retire at tile entry ----
  for (int t = 0; t < NT - 2; ++t) {
    VMW(8);
    BAR();
    TILE(t, t + 3 < NT);
  }
  VMW(4);
  BAR();
  TILE(NT - 2, false);
  VMW(0);
  BAR();
  TILE(NT - 1, false);

  // ======================= LDS-bounce epilogue =============================
  // S[128][256] f32 = 128 KiB, aliasing the (now dead) As/Bs rings.
  // Granule = 16 f32 (64B). Logical col granule g of row r is stored at
  // phys granule g ^ ((r>>2)&3): staging writes (quad q -> swz q) are
  // 2-way/free; row-major read-back (lane -> granule lane>>2) stays a
  // permutation -> conflict-free.
  float* S = (float*)&smem[0][0][0];
  const size_t cz = sC * z;
  float4 bv4;
  if constexpr (EPI == 0) bv4 = *(const float4*)&bias[bn * 256 + lane * 4];

  for (int h = 0; h < 2; ++h) {
    BAR();   // previous S users (main-loop LDS or half h-1 reads) done
    if (wm == h) {
#pragma unroll
      for (int tm = 0; tm < 8; ++tm)
#pragma unroll
        for (int r = 0; r < 4; ++r) {
          const int rloc = tm * 16 + quad * 4 + r;   // (rloc>>2)&3 == quad
#pragma unroll
          for (int tn = 0; tn < 4; ++tn) {
            const int pgw = (wn * 4 + tn) ^ quad;
            S[rloc * 256 + pgw * 16 + l16] = acc[tm][tn][r];
          }
        }
    }
    BAR();
    if (wm == h) {
#pragma unroll
      for (int i = 0; i < 32; ++i) {
        const int rloc = wn * 32 + i;
        const int swz = (i >> 2) & 3;                // == (rloc>>2)&3
        const f32x4 v = *(const f32x4*)&S[rloc * 256 +
                                          (((lane >> 2) ^ swz) << 4) +
                                          ((lane & 3) << 2)];
        const int grow = bm * 256 + h * 128 + rloc;
        const int gcol = bn * 256 + lane * 4;
        const size_t ro = (size_t)grow * N + gcol;
        if constexpr (EPI == 1) {
          const float e0 = __expf(v[0] * scale), e1 = __expf(v[1] * scale),
                      e2 = __expf(v[2] * scale), e3 = __expf(v[3] * scale);
          float part = (e0 + e1) + (e2 + e3);
          const float4 mv =
              *(const float4*)(mask + (size_t)z * 2048 * 2048 + ro);
          ushort4 o;
          o.x = f2bf(e0 * mv.x); o.y = f2bf(e1 * mv.y);
          o.z = f2bf(e2 * mv.z); o.w = f2bf(e3 * mv.w);
          *(ushort4*)((ushort*)Cp + cz + ro) = o;
#pragma unroll
          for (int off = 32; off >= 1; off >>= 1)
            part += __shfl_xor(part, off);
          if (lane == 0)
            atomicAdd(&rowsum[(size_t)z * 2048 + grow], part);
        } else if constexpr (EPI == 2) {
          const float linv = 1.0f / rowsum[(size_t)z * 2048 + grow];
          ushort4 o;
          o.x = f2bf(v[0] * linv); o.y = f2bf(v[1] * linv);
          o.z = f2bf(v[2] * linv); o.w = f2bf(v[3] * linv);
          *(ushort4*)((ushort*)Cp + cz + ro) = o;
        } else {
          float4 o;
          o.x = v[0] * scale + bv4.x; o.y = v[1] * scale + bv4.y;
          o.z = v[2] * scale + bv4.z; o.w = v[3] * scale + bv4.w;
          *(float4*)((float*)Cp + cz + ro) = o;
        }
      }
    }
  }
}

// ---------------------------------------------------------------------------
extern "C" void kernel_launch(void* const* d_in, const int* in_sizes, int n_in,
                              void* d_out, int out_size, void* d_ws,
                              size_t ws_size, hipStream_t stream) {
  (void)in_sizes; (void)n_in; (void)out_size; (void)ws_size;
  const float* Q    = (const float*)d_in[0];
  const float* Kmat = (const float*)d_in[1];
  const float* V    = (const float*)d_in[2];
  const float* mask = (const float*)d_in[3];
  const float* W    = (const float*)d_in[4];
  const float* bout = (const float*)d_in[5];
  float* out = (float*)d_out;

  // ws layout, peak 128 MiB via lifetime reuse:
  //   RegA (32 MiB): Qb during scores -> Vt for PV -> Wb for fc_out
  //   RegB (32 MiB): Kb during scores -> attn from PV
  //   P    (64 MiB): exp-scores (unnormalized, * mask), live scores..PV
  // rowsum [8][2048] f32 (64 KiB) lives at the head of d_out, which is dead
  // until fc_out fully overwrites it.
  ushort* RegA = (ushort*)d_ws;
  ushort* RegB = RegA + (size_t)16 * 1024 * 1024;
  ushort* P    = RegB + (size_t)16 * 1024 * 1024;
  float* rowsum = out;

  // 0) zero softmax denominators (capturable async memset)
  hipMemsetAsync(rowsum, 0, (size_t)8 * 2048 * sizeof(float), stream);
  // 1) Q,K -> bf16 (one dispatch)
  convert_qk_bf16<<<dim3(16384), 256, 0, stream>>>(Q, Kmat, RegA, RegB);
  // 2) P = exp((Qb @ Kb^T)/32) * mask ; rowsum += partials   (fused softmax)
  gemm256<1><<<dim3(8, 8, 8), 512, 0, stream>>>(
      RegA, RegB, P, 2048, 2048, 1024,
      (size_t)2048 * 1024, (size_t)2048 * 1024, (size_t)2048 * 2048,
      1.0f / 32.0f, nullptr, mask, rowsum);
  // 3) V -> V^T bf16 into RegA (Qb now dead)
  transpose_convert_v<<<dim3(16, 32, 8), 256, 0, stream>>>(V, RegA);
  // 4) attn = (P @ Vt) / rowsum -> RegB (Kb now dead)
  gemm256<2><<<dim3(4, 8, 8), 512, 0, stream>>>(
      P, RegA, RegB, 2048, 1024, 2048,
      (size_t)2048 * 2048, (size_t)1024 * 2048, (size_t)2048 * 1024,
      1.0f, nullptr, nullptr, rowsum);
  // 5) W -> bf16 into RegA (Vt now dead)
  convert_w_bf16<<<dim3(512), 256, 0, stream>>>(W, RegA);
  // 6) out = attn @ Wout^T + bout  (fp32 out), batch folded into M
  gemm256<0><<<dim3(4, 64, 1), 512, 0, stream>>>(
      RegB, RegA, out, 16384, 1024, 1024, 0, 0, 0, 1.0f, bout, nullptr,
      nullptr);
}

// Round 6
// 544.895 us; speedup vs baseline: 1.2180x; 1.2180x over previous
//
#include <hip/hip_runtime.h>
#include <cstdint>
#include <cstddef>

typedef short short8 __attribute__((ext_vector_type(8)));
typedef float f32x4 __attribute__((ext_vector_type(4)));

static __device__ __forceinline__ ushort f2bf(float f) {
  union { float f; uint32_t u; } v; v.f = f;
  uint32_t u = v.u + 0x7fffu + ((v.u >> 16) & 1u);  // RNE
  return (ushort)(u >> 16);
}

// Direct global->LDS copy: lane i's 16B lands at lds + i*16 (wave-uniform base).
static __device__ __forceinline__ void g2lds16(const ushort* g, ushort* lds) {
  __builtin_amdgcn_global_load_lds(
      (const __attribute__((address_space(1))) void*)(uintptr_t)g,
      (__attribute__((address_space(3))) void*)(uintptr_t)lds,
      16, 0, 0);
}

#define VMW(n) asm volatile("s_waitcnt vmcnt(" #n ")" ::: "memory")
#define BAR()  asm volatile("s_barrier" ::: "memory")

// ---------------------------------------------------------------------------
// f32 -> bf16 convert for Q and K in one dispatch (8 elem/thread).
// ---------------------------------------------------------------------------
__global__ __launch_bounds__(256) void convert_qk_bf16(
    const float* __restrict__ Q, const float* __restrict__ K,
    ushort* __restrict__ Qb, ushort* __restrict__ Kb) {
  const bool second = blockIdx.x >= 8192;
  const float* src = second ? K : Q;
  ushort* dst = second ? Kb : Qb;
  const size_t i = ((size_t)(blockIdx.x & 8191) * 256 + threadIdx.x) * 8;
  const float4 a = *(const float4*)(src + i);
  const float4 b = *(const float4*)(src + i + 4);
  ushort4 o0, o1;
  o0.x = f2bf(a.x); o0.y = f2bf(a.y); o0.z = f2bf(a.z); o0.w = f2bf(a.w);
  o1.x = f2bf(b.x); o1.y = f2bf(b.y); o1.z = f2bf(b.z); o1.w = f2bf(b.w);
  *(ushort4*)(dst + i) = o0;
  *(ushort4*)(dst + i + 4) = o1;
}

// W [1024][1024] f32 -> bf16 (for the fc_out GEMM)
__global__ __launch_bounds__(256) void convert_w_bf16(
    const float* __restrict__ W, ushort* __restrict__ Wb) {
  const size_t i = ((size_t)blockIdx.x * 256 + threadIdx.x) * 8;
  const float4 a = *(const float4*)(W + i);
  const float4 b = *(const float4*)(W + i + 4);
  ushort4 o0, o1;
  o0.x = f2bf(a.x); o0.y = f2bf(a.y); o0.z = f2bf(a.z); o0.w = f2bf(a.w);
  o1.x = f2bf(b.x); o1.y = f2bf(b.y); o1.z = f2bf(b.z); o1.w = f2bf(b.w);
  *(ushort4*)(Wb + i) = o0;
  *(ushort4*)(Wb + i + 4) = o1;
}

// ---------------------------------------------------------------------------
// V [8][2048][1024] f32 -> Vt [8][1024][2048] bf16.  64x64 tiles so every
// Vt store is a full 128B line.
// ---------------------------------------------------------------------------
__global__ __launch_bounds__(256) void transpose_convert_v(
    const float* __restrict__ V, ushort* __restrict__ Vt) {
  __shared__ float t[64][65];
  const int b = blockIdx.z;
  const int d0 = blockIdx.x * 64;   // gridDim.x = 16
  const int k0 = blockIdx.y * 64;   // gridDim.y = 32
  const float* Vb = V + (size_t)b * 2048 * 1024;
  ushort* Vtb = Vt + (size_t)b * 1024 * 2048;
  const int tx = threadIdx.x & 63, ty = threadIdx.x >> 6;   // 64 x 4
#pragma unroll
  for (int j = 0; j < 64; j += 4)
    t[ty + j][tx] = Vb[(size_t)(k0 + ty + j) * 1024 + d0 + tx];
  __syncthreads();
  const int lk = (threadIdx.x & 31) * 2;   // k-pair within tile
  const int ld = threadIdx.x >> 5;         // 0..7
#pragma unroll
  for (int p = 0; p < 8; ++p) {
    const int d = ld + p * 8;
    const uint32_t val =
        (uint32_t)f2bf(t[lk][d]) | ((uint32_t)f2bf(t[lk + 1][d]) << 16);
    *(uint32_t*)&Vtb[(size_t)(d0 + d) * 2048 + k0 + lk] = val;  // 128B/row
  }
}

// ---------------------------------------------------------------------------
// 256x256-tile "BT" GEMM: C[m][n] = f( sum_k A[m][k]*B[n][k] )
// bf16 A and B. 512 threads = 8 waves (2M x 4N), wave owns 128x64 of C
// (8x4 frags of mfma_f32_16x16x32_bf16; C/D: col=lane&15, row=quad*4+reg).
//
// Main loop (verified rounds 1-3, unchanged): ring-4 of BK=32 K-tiles
// (128 KiB LDS), counted vmcnt, 2-phase interleave per tile, raw barriers,
// setprio around MFMA clusters, XOR-granule LDS swizzle (0 bank conflicts),
// bijective XCD block swizzle.
//
// LDS-bounce epilogue (round 4, FIXED round 5): stage raw f32 acc into
// S[128][256] (one half of the 256-row tile at a time, granule-XOR swizzled;
// writes 2-way/free, reads conflict-free), then read back row-major so all
// global IO is vectorized (float4 mask loads, ushort4/float4 stores, one
// atomicAdd per row).
//   Round-5 fixes for the round-4 scratch-spill regression (WRITE_SIZE
//   +72.7MB = spill signature; full unroll-32 read-back hoisted ~32 float4
//   loads under the 128-VGPR cap):
//     (a) read-back unroll capped at 4  -> bounded in-flight state, no spill
//     (b) read-back uses ALL 8 waves (16 rows each; reading S needs no acc)
//   EPI 0: C f32 = acc*scale + bias[n]                        (fc_out)
//   EPI 1: e=exp(acc*scale); C bf16 = e*mask; rowsum[m] += e  (QK^T fused
//          softmax numerator + dropout; max-subtraction skipped: scores
//          ~N(0,1), exp safe in f32)
//   EPI 2: C bf16 = acc / rowsum[m]                           (PV, denom)
// ---------------------------------------------------------------------------
template <int EPI>
__global__ __launch_bounds__(512, 2) void gemm256(
    const ushort* __restrict__ Ap, const ushort* __restrict__ Bp,
    void* __restrict__ Cp, int M, int N, int K,
    size_t sA, size_t sB, size_t sC, float scale,
    const float* __restrict__ bias, const float* __restrict__ mask,
    float* __restrict__ rowsum) {
  constexpr int BK = 32;
  // [0][*] = A ring, [1][*] = B ring; whole 128 KiB reused by the epilogue.
  __shared__ __align__(16) ushort smem[2][4][256 * BK];
  const int tid = threadIdx.x;

  // ---- T1: XCD-aware block swizzle (nwg divisible by 8 at all call sites) --
  const int gx = gridDim.x, gy = gridDim.y;
  const int nwg = gx * gy * gridDim.z;
  int li = blockIdx.x + gx * (blockIdx.y + gy * blockIdx.z);
  li = (li & 7) * (nwg >> 3) + (li >> 3);
  const int bn = li % gx;
  const int rst = li / gx;
  const int bm = rst % gy;
  const int z = rst / gy;

  const int lane = tid & 63, w = tid >> 6;   // 8 waves
  const int quad = lane >> 4, l16 = lane & 15;
  const int wm = w >> 2, wn = w & 3;         // wave tile: rows wm*128, cols wn*64
  const int NT = K >> 5;                     // K-tiles of 32

  f32x4 acc[8][4];
#pragma unroll
  for (int i = 0; i < 8; ++i)
#pragma unroll
    for (int j = 0; j < 4; ++j) acc[i][j] = (f32x4){0.f, 0.f, 0.f, 0.f};

  // ---- staging addressing (pre-swizzled global source, linear LDS dest) ----
  const int srow = w * 16 + (lane >> 2);                 // row 0..127 (round 0)
  const int sgran = (lane & 3) ^ ((lane >> 3) & 3);      // source granule
  const ushort* Abase = Ap + sA * z + (size_t)bm * 256 * K;
  const ushort* Bbase = Bp + sB * z + (size_t)bn * 256 * K;
  const ushort* Ag0 = Abase + (size_t)srow * K + sgran * 8;
  const ushort* Ag1 = Ag0 + (size_t)128 * K;
  const ushort* Bg0 = Bbase + (size_t)srow * K + sgran * 8;
  const ushort* Bg1 = Bg0 + (size_t)128 * K;
  const int ldsw0 = (w * 16) * BK;         // wave-uniform LDS row block, round 0
  const int ldsw1 = (128 + w * 16) * BK;   // round 1

  auto STAGE_A = [&](int t) {
    ushort* a = &smem[0][t & 3][0];
    const size_t ko = (size_t)t * BK;
    g2lds16(Ag0 + ko, a + ldsw0);
    g2lds16(Ag1 + ko, a + ldsw1);
  };
  auto STAGE_B = [&](int t) {
    ushort* b = &smem[1][t & 3][0];
    const size_t ko = (size_t)t * BK;
    g2lds16(Bg0 + ko, b + ldsw0);
    g2lds16(Bg1 + ko, b + ldsw1);
  };

  // ---- fragment read offsets (swizzled) ----
  const int pg = quad ^ ((l16 >> 1) & 3);                // physical granule
  const int aoff = (wm * 128 + l16) * BK + pg * 8;
  const int boff = (wn * 64 + l16) * BK + pg * 8;

  // One K-tile: 2 phases x 16 MFMA, staging of tile t+3 interleaved.
  auto TILE = [&](int t, bool stage_ok) {
    const ushort* a = &smem[0][t & 3][0];
    const ushort* b = &smem[1][t & 3][0];
    short8 bfv[4], af[4];
#pragma unroll
    for (int tn = 0; tn < 4; ++tn)
      bfv[tn] = *(const short8*)&b[boff + tn * 16 * BK];
#pragma unroll
    for (int tm = 0; tm < 4; ++tm)
      af[tm] = *(const short8*)&a[aoff + tm * 16 * BK];
    if (stage_ok) STAGE_A(t + 3);
    BAR();
    __builtin_amdgcn_s_setprio(1);
#pragma unroll
    for (int tm = 0; tm < 4; ++tm)
#pragma unroll
      for (int tn = 0; tn < 4; ++tn)
        acc[tm][tn] = __builtin_amdgcn_mfma_f32_16x16x32_bf16(
            af[tm], bfv[tn], acc[tm][tn], 0, 0, 0);
    __builtin_amdgcn_s_setprio(0);
    BAR();
    short8 af2[4];
#pragma unroll
    for (int tm = 0; tm < 4; ++tm)
      af2[tm] = *(const short8*)&a[aoff + (4 + tm) * 16 * BK];
    if (stage_ok) STAGE_B(t + 3);
    BAR();
    __builtin_amdgcn_s_setprio(1);
#pragma unroll
    for (int tm = 0; tm < 4; ++tm)
#pragma unroll
      for (int tn = 0; tn < 4; ++tn)
        acc[4 + tm][tn] = __builtin_amdgcn_mfma_f32_16x16x32_bf16(
            af2[tm], bfv[tn], acc[4 + tm][tn], 0, 0, 0);
    __builtin_amdgcn_s_setprio(0);
  };

  // ---- prologue: 3 tiles in flight ----
  STAGE_A(0); STAGE_B(0);
  STAGE_A(1); STAGE_B(1);
  STAGE_A(2); STAGE_B(2);
  // ---- main loop: counted vmcnt, collective retire at tile entry ----
  for (int t = 0; t < NT - 2; ++t) {
    VMW(8);
    BAR();
    TILE(t, t + 3 < NT);
  }
  VMW(4);
  BAR();
  TILE(NT - 2, false);
  VMW(0);
  BAR();
  TILE(NT - 1, false);

  // ======================= LDS-bounce epilogue =============================
  // S[128][256] f32 = 128 KiB, aliasing the (now dead) As/Bs rings.
  // Granule = 16 f32 (64B). Logical col granule g of row r is stored at
  // phys granule g ^ ((r>>2)&3): staging writes are 2-way/free; row-major
  // read-back is a permutation -> conflict-free.
  float* S = (float*)&smem[0][0][0];
  const size_t cz = sC * z;
  float4 bv4;
  if constexpr (EPI == 0) bv4 = *(const float4*)&bias[bn * 256 + lane * 4];

  for (int h = 0; h < 2; ++h) {
    BAR();   // previous S users (main-loop LDS or half h-1 reads) done
    if (wm == h) {   // only the 4 owning waves hold this half's acc
#pragma unroll
      for (int tm = 0; tm < 8; ++tm)
#pragma unroll
        for (int r = 0; r < 4; ++r) {
          const int rloc = tm * 16 + quad * 4 + r;   // (rloc>>2)&3 == quad
#pragma unroll
          for (int tn = 0; tn < 4; ++tn) {
            const int pgw = (wn * 4 + tn) ^ quad;
            S[rloc * 256 + pgw * 16 + l16] = acc[tm][tn][r];
          }
        }
    }
    BAR();
    // read-back: ALL 8 waves, 16 rows each, unroll capped at 4 (spill fix)
#pragma unroll 4
    for (int i = 0; i < 16; ++i) {
      const int rloc = w * 16 + i;
      const int swz = (rloc >> 2) & 3;
      const f32x4 v = *(const f32x4*)&S[rloc * 256 +
                                        (((lane >> 2) ^ swz) << 4) +
                                        ((lane & 3) << 2)];
      const int grow = bm * 256 + h * 128 + rloc;
      const int gcol = bn * 256 + lane * 4;
      const size_t ro = (size_t)grow * N + gcol;
      if constexpr (EPI == 1) {
        const float e0 = __expf(v[0] * scale), e1 = __expf(v[1] * scale),
                    e2 = __expf(v[2] * scale), e3 = __expf(v[3] * scale);
        float part = (e0 + e1) + (e2 + e3);
        const float4 mv = *(const float4*)(mask + (size_t)z * 2048 * 2048 + ro);
        ushort4 o;
        o.x = f2bf(e0 * mv.x); o.y = f2bf(e1 * mv.y);
        o.z = f2bf(e2 * mv.z); o.w = f2bf(e3 * mv.w);
        *(ushort4*)((ushort*)Cp + cz + ro) = o;
#pragma unroll
        for (int off = 32; off >= 1; off >>= 1) part += __shfl_xor(part, off);
        if (lane == 0) atomicAdd(&rowsum[(size_t)z * 2048 + grow], part);
      } else if constexpr (EPI == 2) {
        const float linv = 1.0f / rowsum[(size_t)z * 2048 + grow];
        ushort4 o;
        o.x = f2bf(v[0] * linv); o.y = f2bf(v[1] * linv);
        o.z = f2bf(v[2] * linv); o.w = f2bf(v[3] * linv);
        *(ushort4*)((ushort*)Cp + cz + ro) = o;
      } else {
        float4 o;
        o.x = v[0] * scale + bv4.x; o.y = v[1] * scale + bv4.y;
        o.z = v[2] * scale + bv4.z; o.w = v[3] * scale + bv4.w;
        *(float4*)((float*)Cp + cz + ro) = o;
      }
    }
  }
}

// ---------------------------------------------------------------------------
extern "C" void kernel_launch(void* const* d_in, const int* in_sizes, int n_in,
                              void* d_out, int out_size, void* d_ws,
                              size_t ws_size, hipStream_t stream) {
  (void)in_sizes; (void)n_in; (void)out_size; (void)ws_size;
  const float* Q    = (const float*)d_in[0];
  const float* Kmat = (const float*)d_in[1];
  const float* V    = (const float*)d_in[2];
  const float* mask = (const float*)d_in[3];
  const float* W    = (const float*)d_in[4];
  const float* bout = (const float*)d_in[5];
  float* out = (float*)d_out;

  // ws layout, peak 128 MiB via lifetime reuse:
  //   RegA (32 MiB): Qb during scores -> Vt for PV -> Wb for fc_out
  //   RegB (32 MiB): Kb during scores -> attn from PV
  //   P    (64 MiB): exp-scores (unnormalized, * mask), live scores..PV
  // rowsum [8][2048] f32 (64 KiB) lives at the head of d_out, which is dead
  // until fc_out fully overwrites it.
  ushort* RegA = (ushort*)d_ws;
  ushort* RegB = RegA + (size_t)16 * 1024 * 1024;
  ushort* P    = RegB + (size_t)16 * 1024 * 1024;
  float* rowsum = out;

  // 0) zero softmax denominators (capturable async memset)
  hipMemsetAsync(rowsum, 0, (size_t)8 * 2048 * sizeof(float), stream);
  // 1) Q,K -> bf16 (one dispatch)
  convert_qk_bf16<<<dim3(16384), 256, 0, stream>>>(Q, Kmat, RegA, RegB);
  // 2) P = exp((Qb @ Kb^T)/32) * mask ; rowsum += partials   (fused softmax)
  gemm256<1><<<dim3(8, 8, 8), 512, 0, stream>>>(
      RegA, RegB, P, 2048, 2048, 1024,
      (size_t)2048 * 1024, (size_t)2048 * 1024, (size_t)2048 * 2048,
      1.0f / 32.0f, nullptr, mask, rowsum);
  // 3) V -> V^T bf16 into RegA (Qb now dead)
  transpose_convert_v<<<dim3(16, 32, 8), 256, 0, stream>>>(V, RegA);
  // 4) attn = (P @ Vt) / rowsum -> RegB (Kb now dead)
  gemm256<2><<<dim3(4, 8, 8), 512, 0, stream>>>(
      P, RegA, RegB, 2048, 1024, 2048,
      (size_t)2048 * 2048, (size_t)1024 * 2048, (size_t)2048 * 1024,
      1.0f, nullptr, nullptr, rowsum);
  // 5) W -> bf16 into RegA (Vt now dead)
  convert_w_bf16<<<dim3(512), 256, 0, stream>>>(W, RegA);
  // 6) out = attn @ Wout^T + bout  (fp32 out), batch folded into M
  gemm256<0><<<dim3(4, 64, 1), 512, 0, stream>>>(
      RegB, RegA, out, 16384, 1024, 1024, 0, 0, 0, 1.0f, bout, nullptr,
      nullptr);
}